// Round 1
// 849.238 us; speedup vs baseline: 1.1626x; 1.1626x over previous
//
#include <hip/hip_runtime.h>
#include <stdint.h>

#define NT 500000
#define NC 100000
#define NM 20000
#define NE 500000

// ---------- small dense precompute: Weq = W1 @ Wf, beq = b1 @ Wf ----------
__global__ __launch_bounds__(256) void weq_kernel(const float* __restrict__ W1c,
                                                  const float* __restrict__ b1c,
                                                  const float* __restrict__ W1m,
                                                  const float* __restrict__ b1m,
                                                  const float* __restrict__ Wf,
                                                  float* __restrict__ WeqC,
                                                  float* __restrict__ WeqM,
                                                  float* __restrict__ beq) {
    int t = threadIdx.x;
    if (t < 128) {
        int k = t >> 1, o = t & 1;
        float s = 0.0f;
        for (int j = 0; j < 64; j++) s += W1c[k * 64 + j] * Wf[j * 2 + o];
        WeqC[k * 2 + o] = s;
    } else {
        int k = (t - 128) >> 1, o = t & 1;
        float s = 0.0f;
        for (int j = 0; j < 64; j++) s += W1m[k * 64 + j] * Wf[j * 2 + o];
        WeqM[k * 2 + o] = s;
    }
    if (t < 4) {
        const float* b = (t < 2) ? b1c : b1m;
        int o = t & 1;
        float s = 0.0f;
        for (int j = 0; j < 64; j++) s += b[j] * Wf[j * 2 + o];
        beq[t] = s;
    }
}

// ---------- CSR build (both relations per launch) ----------
__global__ __launch_bounds__(256) void hist_both(const int* __restrict__ dstC,
                                                 const int* __restrict__ dstM,
                                                 int* __restrict__ cntC,
                                                 int* __restrict__ cntM) {
    int e = blockIdx.x * 256 + threadIdx.x;
    if (e < NE) {
        atomicAdd(&cntC[dstC[e]], 1);
    } else {
        e -= NE;
        if (e < NE) atomicAdd(&cntM[dstM[e]], 1);
    }
}

// blocks 0..97 sum C counts, 98..117 sum M counts (1024 counts per block)
__global__ __launch_bounds__(256) void blocksum_both(const int* __restrict__ cC,
                                                     const int* __restrict__ cM,
                                                     int* __restrict__ blkC,
                                                     int* __restrict__ blkM) {
    int b = blockIdx.x;
    const int* counts; int* blk; int n, bb;
    if (b < 98) { counts = cC; blk = blkC; n = NC; bb = b; }
    else        { counts = cM; blk = blkM; n = NM; bb = b - 98; }
    int tid = threadIdx.x;
    int base = bb * 1024 + tid * 4;
    int s = 0;
#pragma unroll
    for (int j = 0; j < 4; j++) { int i = base + j; if (i < n) s += counts[i]; }
    for (int off = 32; off; off >>= 1) s += __shfl_down(s, off, 64);
    __shared__ int wsum[4];
    if ((tid & 63) == 0) wsum[tid >> 6] = s;
    __syncthreads();
    if (tid == 0) blk[bb] = wsum[0] + wsum[1] + wsum[2] + wsum[3];
}

// block 0: scan blkC[0..98); block 1: scan blkM[0..20)
__global__ __launch_bounds__(256) void scanblk_both(int* __restrict__ blkC,
                                                    int* __restrict__ blkM) {
    int* blk; int nb;
    if (blockIdx.x == 0) { blk = blkC; nb = 98; }
    else                 { blk = blkM; nb = 20; }
    __shared__ int sh[256];
    int tid = threadIdx.x;
    int v = tid < nb ? blk[tid] : 0;
    sh[tid] = v; __syncthreads();
    for (int off = 1; off < 256; off <<= 1) {
        int t = (tid >= off) ? sh[tid - off] : 0;
        __syncthreads();
        sh[tid] += t;
        __syncthreads();
    }
    if (tid < nb) blk[tid] = sh[tid] - v;   // exclusive
}

// blocks 0..97 -> C, 98..117 -> M: exclusive-scan 1024 counts in place,
// init cursor, write rowPtr[n] from owner of element n-1.
__global__ __launch_bounds__(256) void scanfinal_both(int* __restrict__ rowPtrC,
                                                      int* __restrict__ cursorC,
                                                      const int* __restrict__ blkC,
                                                      int* __restrict__ rowPtrM,
                                                      int* __restrict__ cursorM,
                                                      const int* __restrict__ blkM) {
    int b = blockIdx.x;
    int* rowPtr; int* cursor; const int* blkOff; int n, bb;
    if (b < 98) { rowPtr = rowPtrC; cursor = cursorC; blkOff = blkC; n = NC; bb = b; }
    else        { rowPtr = rowPtrM; cursor = cursorM; blkOff = blkM; n = NM; bb = b - 98; }
    int tid = threadIdx.x, lane = tid & 63, wv = tid >> 6;
    int base = bb * 1024 + tid * 4;
    int c[4];
#pragma unroll
    for (int j = 0; j < 4; j++) { int i = base + j; c[j] = (i < n) ? rowPtr[i] : 0; }
    int t = c[0] + c[1] + c[2] + c[3];
    int incl = t;
    for (int off = 1; off < 64; off <<= 1) {
        int u = __shfl_up(incl, off, 64);
        if (lane >= off) incl += u;
    }
    int lexcl = incl - t;
    __shared__ int wsum[4], woff[4];
    if (lane == 63) wsum[wv] = incl;
    __syncthreads();
    if (tid == 0) { int a = 0; for (int w = 0; w < 4; w++) { woff[w] = a; a += wsum[w]; } }
    __syncthreads();
    int e = blkOff[bb] + woff[wv] + lexcl;
#pragma unroll
    for (int j = 0; j < 4; j++) {
        int i = base + j;
        if (i < n) {
            rowPtr[i] = e;
            cursor[i] = e;
            if (i == n - 1) rowPtr[n] = e + c[j];
        }
        e += c[j];
    }
}

__global__ __launch_bounds__(256) void scatter_both(const int* __restrict__ srcC,
                                                    const int* __restrict__ dstC,
                                                    int* __restrict__ cursorC,
                                                    int* __restrict__ eidxC,
                                                    const int* __restrict__ srcM,
                                                    const int* __restrict__ dstM,
                                                    int* __restrict__ cursorM,
                                                    int* __restrict__ eidxM) {
    int e = blockIdx.x * 256 + threadIdx.x;
    if (e < NE) {
        int pos = atomicAdd(&cursorC[dstC[e]], 1);
        eidxC[pos] = srcC[e];
    } else {
        e -= NE;
        if (e < NE) {
            int pos = atomicAdd(&cursorM[dstM[e]], 1);
            eidxM[pos] = srcM[e];
        }
    }
}

// ---------- gather aggregation: one wave per dst node, no atomics ----------
// half-wave (32 lanes x float4 = 512B) per edge; two edges in flight; xor-combine.
__global__ __launch_bounds__(256) void agg_csr(const float* __restrict__ feat,
                                               const int* __restrict__ rowPtr,
                                               const int* __restrict__ eidx,
                                               float* __restrict__ sum,
                                               int base, int nNodes) {
    int gw = (blockIdx.x * 256 + threadIdx.x) >> 6;
    if (gw >= nNodes) return;
    int lane = threadIdx.x & 63;
    int half = lane >> 5;            // 0 or 1: which edge of the pair
    int c4 = (lane & 31) * 4;        // channel offset
    int d = base + gw;
    int s0 = rowPtr[d], s1 = rowPtr[d + 1];
    float a0 = 0.f, a1 = 0.f, a2 = 0.f, a3 = 0.f;
    int i = s0;
    for (; i + 1 < s1; i += 2) {
        int s = eidx[i + half];
        const float4 v = *(const float4*)(feat + (size_t)s * 128 + c4);
        a0 += v.x; a1 += v.y; a2 += v.z; a3 += v.w;
    }
    if (i < s1 && half == 0) {
        int s = eidx[i];
        const float4 v = *(const float4*)(feat + (size_t)s * 128 + c4);
        a0 += v.x; a1 += v.y; a2 += v.z; a3 += v.w;
    }
    a0 += __shfl_xor(a0, 32, 64);
    a1 += __shfl_xor(a1, 32, 64);
    a2 += __shfl_xor(a2, 32, 64);
    a3 += __shfl_xor(a3, 32, 64);
    if (half == 0) {
        float4 o; o.x = a0; o.y = a1; o.z = a2; o.w = a3;
        *(float4*)(sum + (size_t)gw * 128 + c4) = o;
    }
}

// ---------- fused: h1 = cnt>0 ? leaky(sum/cnt @ W0 + b0) : 0 ; p = h1 @ Weq ----------
// Rewritten: 32 rows/block, k-outer loop so each Ws read is amortized over 8 rows,
// sums read as wave-uniform broadcast float4, shfl-butterfly epilogue (no LDS atomics).
__global__ __launch_bounds__(256) void h1proj(const float* __restrict__ sum,
                                              const int* __restrict__ rowPtrB,
                                              const float* __restrict__ W0,
                                              const float* __restrict__ b0,
                                              const float* __restrict__ Weq,
                                              float* __restrict__ p, int n) {
    __shared__ float Ws[128 * 64];    // 32 KB
    __shared__ float sums[32 * 128];  // 16 KB
    int tid = threadIdx.x;
    int base = blockIdx.x * 32;
    {   // cooperative W0 load, float4 (coalesced, 8 iters/thread)
        const float4* W4 = (const float4*)W0;
        float4* Ws4 = (float4*)Ws;
        for (int i = tid; i < 128 * 64 / 4; i += 256) Ws4[i] = W4[i];
    }
    {   // cooperative sums load, float4 (4 iters/thread); rows are contiguous
        const float4* S4 = (const float4*)sum;
        float4* s4 = (float4*)sums;
        for (int i = tid; i < 32 * 128 / 4; i += 256) {
            int r = i >> 5;                       // 32 float4 per row
            int row = base + r;
            float4 v;
            if (row < n) v = S4[(size_t)base * 32 + i];
            else { v.x = v.y = v.z = v.w = 0.0f; }
            s4[i] = v;
        }
    }
    __syncthreads();
    int col = tid & 63, wv = tid >> 6;            // wave owns rows wv*8 .. wv*8+7
    float acc[8];
#pragma unroll
    for (int r = 0; r < 8; r++) acc[r] = 0.0f;
    const float* srow = &sums[wv * 8 * 128];
    for (int k = 0; k < 128; k += 4) {
        // per-lane Ws reads: bank = col%32 -> 2-way (free); amortized over 8 rows
        float w0_ = Ws[(k + 0) * 64 + col];
        float w1_ = Ws[(k + 1) * 64 + col];
        float w2_ = Ws[(k + 2) * 64 + col];
        float w3_ = Ws[(k + 3) * 64 + col];
#pragma unroll
        for (int r = 0; r < 8; r++) {
            const float4 s = *(const float4*)&srow[r * 128 + k];  // broadcast
            acc[r] += s.x * w0_ + s.y * w1_ + s.z * w2_ + s.w * w3_;
        }
    }
    float b0c = b0[col];
    float wq0 = Weq[col * 2 + 0], wq1 = Weq[col * 2 + 1];
#pragma unroll
    for (int r = 0; r < 8; r++) {
        int row = base + wv * 8 + r;
        int cn = 0;
        if (row < n) cn = rowPtrB[row + 1] - rowPtrB[row];
        float h = 0.0f;
        if (cn > 0) {
            float v = acc[r] / (float)cn + b0c;
            h = v > 0.0f ? v : 0.01f * v;
        }
        float p0 = h * wq0, p1 = h * wq1;
#pragma unroll
        for (int off = 32; off; off >>= 1) {
            p0 += __shfl_down(p0, off, 64);
            p1 += __shfl_down(p1, off, 64);
        }
        if (col == 0 && row < n) {
            p[(size_t)row * 2 + 0] = p0;
            p[(size_t)row * 2 + 1] = p1;
        }
    }
}

// ---------- layer-1 projected aggregation (2 ch), both relations ----------
__global__ __launch_bounds__(256) void agg2_both(const float* __restrict__ pC,
                                                 const int* __restrict__ srcC,
                                                 const int* __restrict__ dstC,
                                                 float* __restrict__ accC,
                                                 float* __restrict__ cntC,
                                                 const float* __restrict__ pM,
                                                 const int* __restrict__ srcM,
                                                 const int* __restrict__ dstM,
                                                 float* __restrict__ accM,
                                                 float* __restrict__ cntM) {
    int e = blockIdx.x * 256 + threadIdx.x;
    const float* p; const int* src; const int* dst; float* acc; float* cnt;
    if (e < NE) { p = pC; src = srcC; dst = dstC; acc = accC; cnt = cntC; }
    else {
        e -= NE;
        if (e >= NE) return;
        p = pM; src = srcM; dst = dstM; acc = accM; cnt = cntM;
    }
    int s = src[e], d = dst[e];
    const float2 v = *(const float2*)(p + (size_t)s * 2);
    atomicAdd(acc + (size_t)d * 2 + 0, v.x);
    atomicAdd(acc + (size_t)d * 2 + 1, v.y);
    atomicAdd(cnt + d, 1.0f);
}

__global__ __launch_bounds__(256) void final_kernel(const float* __restrict__ accC,
                                                    const float* __restrict__ cntC,
                                                    const float* __restrict__ accM,
                                                    const float* __restrict__ cntM,
                                                    const float* __restrict__ beq,
                                                    const float* __restrict__ bfv,
                                                    float* __restrict__ out) {
    int i = blockIdx.x * 256 + threadIdx.x;
    if (i >= NT) return;
    float r0 = bfv[0], r1 = bfv[1];
    float cc = cntC[i], cm = cntM[i];
    if (cc > 0.0f) {
        float inv = 1.0f / cc;
        r0 += accC[(size_t)i * 2 + 0] * inv + beq[0];
        r1 += accC[(size_t)i * 2 + 1] * inv + beq[1];
    }
    if (cm > 0.0f) {
        float inv = 1.0f / cm;
        r0 += accM[(size_t)i * 2 + 0] * inv + beq[2];
        r1 += accM[(size_t)i * 2 + 1] * inv + beq[3];
    }
    float2 o; o.x = r0; o.y = r1;
    *(float2*)(out + (size_t)i * 2) = o;
}

extern "C" void kernel_launch(void* const* d_in, const int* in_sizes, int n_in,
                              void* d_out, int out_size, void* d_ws, size_t ws_size,
                              hipStream_t stream) {
    const float* feat = (const float*)d_in[0];
    const int* src_c2t = (const int*)d_in[3];
    const int* dst_c2t = (const int*)d_in[4];
    const int* src_m2t = (const int*)d_in[5];
    const int* dst_m2t = (const int*)d_in[6];
    const int* src_t2c = (const int*)d_in[7];
    const int* dst_t2c = (const int*)d_in[8];
    const int* src_t2m = (const int*)d_in[9];
    const int* dst_t2m = (const int*)d_in[10];
    const float* W1_c2t = (const float*)d_in[13];
    const float* b1_c2t = (const float*)d_in[14];
    const float* W1_m2t = (const float*)d_in[17];
    const float* b1_m2t = (const float*)d_in[18];
    const float* W0_t2c = (const float*)d_in[19];
    const float* b0_t2c = (const float*)d_in[20];
    const float* W0_t2m = (const float*)d_in[23];
    const float* b0_t2m = (const float*)d_in[24];
    const float* Wf  = (const float*)d_in[27];
    const float* bfv = (const float*)d_in[28];

    char* ws = (char*)d_ws;
    // Non-overlapping layout, max footprint ~43.5 MB (< 52.6 MB proven safe).
    // acc/cnt no longer alias SUM -> their 12 MB zero-fill issues up front.
    float* SUM     = (float*)(ws + 0);           // 25.6 MB (50000x128 chunk, reused 3x)
    int*   rowPtrC = (int*)(ws + 25600000);      // 400,016
    int*   rowPtrM = (int*)(ws + 26000016);      // 80,016 (adjacent: one memset)
    int*   cursorC = (int*)(ws + 26080032);      // 400,000
    int*   cursorM = (int*)(ws + 26480032);      // 80,000
    int*   eidxC   = (int*)(ws + 26560032);      // 2,000,000
    int*   eidxM   = (int*)(ws + 28560032);      // 2,000,000
    float* pC      = (float*)(ws + 30560032);    // 800,000
    float* pM      = (float*)(ws + 31360032);    // 160,000
    float* WeqC    = (float*)(ws + 31520032);
    float* WeqM    = (float*)(ws + 31520544);
    float* beq     = (float*)(ws + 31521056);
    int*   blkC    = (int*)(ws + 31521088);      // 98 ints
    int*   blkM    = (int*)(ws + 31521600);      // 20 ints
    float* accC    = (float*)(ws + 31522112);    // 4 MB
    float* cntCT   = (float*)(ws + 35522112);    // 2 MB
    float* accM    = (float*)(ws + 37522112);    // 4 MB
    float* cntMT   = (float*)(ws + 41522112);    // 2 MB  (end ~43.5 MB)

    // independent fills first
    hipMemsetAsync(rowPtrC, 0, 480032, stream);       // rowPtrC + rowPtrM
    hipMemsetAsync(accC, 0, 12000000, stream);        // acc/cnt for layer 1

    weq_kernel<<<1, 256, 0, stream>>>(W1_c2t, b1_c2t, W1_m2t, b1_m2t, Wf, WeqC, WeqM, beq);

    // ---- build CSR for t2c and t2m (merged launches) ----
    hist_both<<<3907, 256, 0, stream>>>(dst_t2c, dst_t2m, rowPtrC, rowPtrM);
    blocksum_both<<<118, 256, 0, stream>>>(rowPtrC, rowPtrM, blkC, blkM);
    scanblk_both<<<2, 256, 0, stream>>>(blkC, blkM);
    scanfinal_both<<<118, 256, 0, stream>>>(rowPtrC, cursorC, blkC, rowPtrM, cursorM, blkM);
    scatter_both<<<3907, 256, 0, stream>>>(src_t2c, dst_t2c, cursorC, eidxC,
                                           src_t2m, dst_t2m, cursorM, eidxM);

    // ---- layer 0: gather-aggregate + fused projection, chunked ----
    agg_csr<<<12500, 256, 0, stream>>>(feat, rowPtrC, eidxC, SUM, 0, 50000);
    h1proj<<<1563, 256, 0, stream>>>(SUM, rowPtrC, W0_t2c, b0_t2c, WeqC, pC, 50000);
    agg_csr<<<12500, 256, 0, stream>>>(feat, rowPtrC, eidxC, SUM, 50000, 50000);
    h1proj<<<1563, 256, 0, stream>>>(SUM, rowPtrC + 50000, W0_t2c, b0_t2c, WeqC, pC + 100000, 50000);
    agg_csr<<<5000, 256, 0, stream>>>(feat, rowPtrM, eidxM, SUM, 0, 20000);
    h1proj<<<625, 256, 0, stream>>>(SUM, rowPtrM, W0_t2m, b0_t2m, WeqM, pM, 20000);

    // ---- layer 1 (2-channel) ----
    agg2_both<<<3907, 256, 0, stream>>>(pC, src_c2t, dst_c2t, accC, cntCT,
                                        pM, src_m2t, dst_m2t, accM, cntMT);
    final_kernel<<<1954, 256, 0, stream>>>(accC, cntCT, accM, cntMT, beq, bfv, (float*)d_out);
}

// Round 2
// 825.699 us; speedup vs baseline: 1.1957x; 1.0285x over previous
//
#include <hip/hip_runtime.h>
#include <stdint.h>

#define NT 500000
#define NC 100000
#define NM 20000
#define NE 500000

// ---------- small dense precompute: Weq = W1 @ Wf, beq = b1 @ Wf ----------
__global__ __launch_bounds__(256) void weq_kernel(const float* __restrict__ W1c,
                                                  const float* __restrict__ b1c,
                                                  const float* __restrict__ W1m,
                                                  const float* __restrict__ b1m,
                                                  const float* __restrict__ Wf,
                                                  float* __restrict__ WeqC,
                                                  float* __restrict__ WeqM,
                                                  float* __restrict__ beq) {
    int t = threadIdx.x;
    if (t < 128) {
        int k = t >> 1, o = t & 1;
        float s = 0.0f;
        for (int j = 0; j < 64; j++) s += W1c[k * 64 + j] * Wf[j * 2 + o];
        WeqC[k * 2 + o] = s;
    } else {
        int k = (t - 128) >> 1, o = t & 1;
        float s = 0.0f;
        for (int j = 0; j < 64; j++) s += W1m[k * 64 + j] * Wf[j * 2 + o];
        WeqM[k * 2 + o] = s;
    }
    if (t < 4) {
        const float* b = (t < 2) ? b1c : b1m;
        int o = t & 1;
        float s = 0.0f;
        for (int j = 0; j < 64; j++) s += b[j] * Wf[j * 2 + o];
        beq[t] = s;
    }
}

// ---------- CSR build: ALL FOUR relations per launch ----------
// region 0: t2c -> cntC (NC bins)   region 1: t2m -> cntM (NM bins)
// region 2: c2t -> cntTC (NT bins)  region 3: m2t -> cntTM (NT bins)
__global__ __launch_bounds__(256) void hist4(const int* __restrict__ dTC,
                                             const int* __restrict__ dTM,
                                             const int* __restrict__ dCT,
                                             const int* __restrict__ dMT,
                                             int* __restrict__ cC,
                                             int* __restrict__ cM,
                                             int* __restrict__ cTC,
                                             int* __restrict__ cTM) {
    int id = blockIdx.x * 256 + threadIdx.x;
    int r = id / NE;
    int e = id - r * NE;
    if (r == 0)      atomicAdd(&cC[dTC[e]], 1);
    else if (r == 1) atomicAdd(&cM[dTM[e]], 1);
    else if (r == 2) atomicAdd(&cTC[dCT[e]], 1);
    else if (r == 3) atomicAdd(&cTM[dMT[e]], 1);
}

// blocks: [0,98) C | [98,118) M | [118,607) TC | [607,1096) TM ; 1024 counts/block
__global__ __launch_bounds__(256) void blocksum4(const int* __restrict__ cC,
                                                 const int* __restrict__ cM,
                                                 const int* __restrict__ cTC,
                                                 const int* __restrict__ cTM,
                                                 int* __restrict__ blkC,
                                                 int* __restrict__ blkM,
                                                 int* __restrict__ blkTC,
                                                 int* __restrict__ blkTM) {
    int b = blockIdx.x;
    const int* counts; int* blk; int n, bb;
    if (b < 98)       { counts = cC;  blk = blkC;  n = NC; bb = b; }
    else if (b < 118) { counts = cM;  blk = blkM;  n = NM; bb = b - 98; }
    else if (b < 607) { counts = cTC; blk = blkTC; n = NT; bb = b - 118; }
    else              { counts = cTM; blk = blkTM; n = NT; bb = b - 607; }
    int tid = threadIdx.x;
    int base = bb * 1024 + tid * 4;
    int s = 0;
#pragma unroll
    for (int j = 0; j < 4; j++) { int i = base + j; if (i < n) s += counts[i]; }
    for (int off = 32; off; off >>= 1) s += __shfl_down(s, off, 64);
    __shared__ int wsum[4];
    if ((tid & 63) == 0) wsum[tid >> 6] = s;
    __syncthreads();
    if (tid == 0) blk[bb] = wsum[0] + wsum[1] + wsum[2] + wsum[3];
}

// 4 blocks; each exclusive-scans one blk array (nb up to 489 <= 512 capacity)
__global__ __launch_bounds__(256) void scanblk4(int* __restrict__ blkC,
                                                int* __restrict__ blkM,
                                                int* __restrict__ blkTC,
                                                int* __restrict__ blkTM) {
    int* blk; int nb;
    if (blockIdx.x == 0)      { blk = blkC;  nb = 98; }
    else if (blockIdx.x == 1) { blk = blkM;  nb = 20; }
    else if (blockIdx.x == 2) { blk = blkTC; nb = 489; }
    else                      { blk = blkTM; nb = 489; }
    __shared__ int ps[256];
    int tid = threadIdx.x;
    int i0 = 2 * tid, i1 = i0 + 1;
    int a = (i0 < nb) ? blk[i0] : 0;
    int b = (i1 < nb) ? blk[i1] : 0;
    ps[tid] = a + b;
    __syncthreads();
    for (int off = 1; off < 256; off <<= 1) {
        int t = (tid >= off) ? ps[tid - off] : 0;
        __syncthreads();
        ps[tid] += t;
        __syncthreads();
    }
    int excl = ps[tid] - (a + b);
    if (i0 < nb) blk[i0] = excl;
    if (i1 < nb) blk[i1] = excl + a;
}

// same block mapping as blocksum4: exclusive-scan 1024 counts in place,
// init cursor, write rowPtr[n] from owner of element n-1.
__global__ __launch_bounds__(256) void scanfinal4(int* __restrict__ rowPtrC,
                                                  int* __restrict__ cursorC,
                                                  const int* __restrict__ blkC,
                                                  int* __restrict__ rowPtrM,
                                                  int* __restrict__ cursorM,
                                                  const int* __restrict__ blkM,
                                                  int* __restrict__ rowPtrTC,
                                                  int* __restrict__ cursorTC,
                                                  const int* __restrict__ blkTC,
                                                  int* __restrict__ rowPtrTM,
                                                  int* __restrict__ cursorTM,
                                                  const int* __restrict__ blkTM) {
    int b = blockIdx.x;
    int* rowPtr; int* cursor; const int* blkOff; int n, bb;
    if (b < 98)       { rowPtr = rowPtrC;  cursor = cursorC;  blkOff = blkC;  n = NC; bb = b; }
    else if (b < 118) { rowPtr = rowPtrM;  cursor = cursorM;  blkOff = blkM;  n = NM; bb = b - 98; }
    else if (b < 607) { rowPtr = rowPtrTC; cursor = cursorTC; blkOff = blkTC; n = NT; bb = b - 118; }
    else              { rowPtr = rowPtrTM; cursor = cursorTM; blkOff = blkTM; n = NT; bb = b - 607; }
    int tid = threadIdx.x, lane = tid & 63, wv = tid >> 6;
    int base = bb * 1024 + tid * 4;
    int c[4];
#pragma unroll
    for (int j = 0; j < 4; j++) { int i = base + j; c[j] = (i < n) ? rowPtr[i] : 0; }
    int t = c[0] + c[1] + c[2] + c[3];
    int incl = t;
    for (int off = 1; off < 64; off <<= 1) {
        int u = __shfl_up(incl, off, 64);
        if (lane >= off) incl += u;
    }
    int lexcl = incl - t;
    __shared__ int wsum[4], woff[4];
    if (lane == 63) wsum[wv] = incl;
    __syncthreads();
    if (tid == 0) { int a = 0; for (int w = 0; w < 4; w++) { woff[w] = a; a += wsum[w]; } }
    __syncthreads();
    int e = blkOff[bb] + woff[wv] + lexcl;
#pragma unroll
    for (int j = 0; j < 4; j++) {
        int i = base + j;
        if (i < n) {
            rowPtr[i] = e;
            cursor[i] = e;
            if (i == n - 1) rowPtr[n] = e + c[j];
        }
        e += c[j];
    }
}

__global__ __launch_bounds__(256) void scatter4(const int* __restrict__ sTC,
                                                const int* __restrict__ dTC,
                                                int* __restrict__ curC,
                                                int* __restrict__ eidxC,
                                                const int* __restrict__ sTM,
                                                const int* __restrict__ dTM,
                                                int* __restrict__ curM,
                                                int* __restrict__ eidxM,
                                                const int* __restrict__ sCT,
                                                const int* __restrict__ dCT,
                                                int* __restrict__ curTC,
                                                int* __restrict__ eidxTC,
                                                const int* __restrict__ sMT,
                                                const int* __restrict__ dMT,
                                                int* __restrict__ curTM,
                                                int* __restrict__ eidxTM) {
    int id = blockIdx.x * 256 + threadIdx.x;
    int r = id / NE;
    int e = id - r * NE;
    if (r == 0)      { int p = atomicAdd(&curC[dTC[e]], 1);  eidxC[p]  = sTC[e]; }
    else if (r == 1) { int p = atomicAdd(&curM[dTM[e]], 1);  eidxM[p]  = sTM[e]; }
    else if (r == 2) { int p = atomicAdd(&curTC[dCT[e]], 1); eidxTC[p] = sCT[e]; }
    else if (r == 3) { int p = atomicAdd(&curTM[dMT[e]], 1); eidxTM[p] = sMT[e]; }
}

// ---------- gather aggregation: one wave per dst node, no atomics ----------
__global__ __launch_bounds__(256) void agg_csr(const float* __restrict__ feat,
                                               const int* __restrict__ rowPtr,
                                               const int* __restrict__ eidx,
                                               float* __restrict__ sum,
                                               int base, int nNodes) {
    int gw = (blockIdx.x * 256 + threadIdx.x) >> 6;
    if (gw >= nNodes) return;
    int lane = threadIdx.x & 63;
    int half = lane >> 5;            // 0 or 1: which edge of the pair
    int c4 = (lane & 31) * 4;        // channel offset
    int d = base + gw;
    int s0 = rowPtr[d], s1 = rowPtr[d + 1];
    float a0 = 0.f, a1 = 0.f, a2 = 0.f, a3 = 0.f;
    int i = s0;
    for (; i + 1 < s1; i += 2) {
        int s = eidx[i + half];
        const float4 v = *(const float4*)(feat + (size_t)s * 128 + c4);
        a0 += v.x; a1 += v.y; a2 += v.z; a3 += v.w;
    }
    if (i < s1 && half == 0) {
        int s = eidx[i];
        const float4 v = *(const float4*)(feat + (size_t)s * 128 + c4);
        a0 += v.x; a1 += v.y; a2 += v.z; a3 += v.w;
    }
    a0 += __shfl_xor(a0, 32, 64);
    a1 += __shfl_xor(a1, 32, 64);
    a2 += __shfl_xor(a2, 32, 64);
    a3 += __shfl_xor(a3, 32, 64);
    if (half == 0) {
        float4 o; o.x = a0; o.y = a1; o.z = a2; o.w = a3;
        *(float4*)(sum + (size_t)gw * 128 + c4) = o;
    }
}

// ---------- fused: h1 = cnt>0 ? leaky(sum/cnt @ W0 + b0) : 0 ; p = h1 @ Weq ----------
__global__ __launch_bounds__(256) void h1proj(const float* __restrict__ sum,
                                              const int* __restrict__ rowPtrB,
                                              const float* __restrict__ W0,
                                              const float* __restrict__ b0,
                                              const float* __restrict__ Weq,
                                              float* __restrict__ p, int n) {
    __shared__ float Ws[128 * 64];    // 32 KB
    __shared__ float sums[32 * 128];  // 16 KB
    int tid = threadIdx.x;
    int base = blockIdx.x * 32;
    {
        const float4* W4 = (const float4*)W0;
        float4* Ws4 = (float4*)Ws;
        for (int i = tid; i < 128 * 64 / 4; i += 256) Ws4[i] = W4[i];
    }
    {
        const float4* S4 = (const float4*)sum;
        float4* s4 = (float4*)sums;
        for (int i = tid; i < 32 * 128 / 4; i += 256) {
            int r = i >> 5;
            int row = base + r;
            float4 v;
            if (row < n) v = S4[(size_t)base * 32 + i];
            else { v.x = v.y = v.z = v.w = 0.0f; }
            s4[i] = v;
        }
    }
    __syncthreads();
    int col = tid & 63, wv = tid >> 6;
    float acc[8];
#pragma unroll
    for (int r = 0; r < 8; r++) acc[r] = 0.0f;
    const float* srow = &sums[wv * 8 * 128];
    for (int k = 0; k < 128; k += 4) {
        float w0_ = Ws[(k + 0) * 64 + col];
        float w1_ = Ws[(k + 1) * 64 + col];
        float w2_ = Ws[(k + 2) * 64 + col];
        float w3_ = Ws[(k + 3) * 64 + col];
#pragma unroll
        for (int r = 0; r < 8; r++) {
            const float4 s = *(const float4*)&srow[r * 128 + k];
            acc[r] += s.x * w0_ + s.y * w1_ + s.z * w2_ + s.w * w3_;
        }
    }
    float b0c = b0[col];
    float wq0 = Weq[col * 2 + 0], wq1 = Weq[col * 2 + 1];
#pragma unroll
    for (int r = 0; r < 8; r++) {
        int row = base + wv * 8 + r;
        int cn = 0;
        if (row < n) cn = rowPtrB[row + 1] - rowPtrB[row];
        float h = 0.0f;
        if (cn > 0) {
            float v = acc[r] / (float)cn + b0c;
            h = v > 0.0f ? v : 0.01f * v;
        }
        float p0 = h * wq0, p1 = h * wq1;
#pragma unroll
        for (int off = 32; off; off >>= 1) {
            p0 += __shfl_down(p0, off, 64);
            p1 += __shfl_down(p1, off, 64);
        }
        if (col == 0 && row < n) {
            p[(size_t)row * 2 + 0] = p0;
            p[(size_t)row * 2 + 1] = p1;
        }
    }
}

// ---------- layer 1: CSR gather (no atomics) fused with final linear ----------
__global__ __launch_bounds__(256) void gather_final(const float* __restrict__ pC,
                                                    const int* __restrict__ rowPtrTC,
                                                    const int* __restrict__ eidxTC,
                                                    const float* __restrict__ pM,
                                                    const int* __restrict__ rowPtrTM,
                                                    const int* __restrict__ eidxTM,
                                                    const float* __restrict__ beq,
                                                    const float* __restrict__ bfv,
                                                    float* __restrict__ out) {
    int i = blockIdx.x * 256 + threadIdx.x;
    if (i >= NT) return;
    float r0 = bfv[0], r1 = bfv[1];
    {
        int s0 = rowPtrTC[i], s1 = rowPtrTC[i + 1];
        if (s1 > s0) {
            float a0 = 0.f, a1 = 0.f;
            for (int e = s0; e < s1; e++) {
                int s = eidxTC[e];
                const float2 v = *(const float2*)(pC + (size_t)s * 2);
                a0 += v.x; a1 += v.y;
            }
            float inv = 1.0f / (float)(s1 - s0);
            r0 += a0 * inv + beq[0];
            r1 += a1 * inv + beq[1];
        }
    }
    {
        int s0 = rowPtrTM[i], s1 = rowPtrTM[i + 1];
        if (s1 > s0) {
            float a0 = 0.f, a1 = 0.f;
            for (int e = s0; e < s1; e++) {
                int s = eidxTM[e];
                const float2 v = *(const float2*)(pM + (size_t)s * 2);
                a0 += v.x; a1 += v.y;
            }
            float inv = 1.0f / (float)(s1 - s0);
            r0 += a0 * inv + beq[2];
            r1 += a1 * inv + beq[3];
        }
    }
    float2 o; o.x = r0; o.y = r1;
    *(float2*)(out + (size_t)i * 2) = o;
}

extern "C" void kernel_launch(void* const* d_in, const int* in_sizes, int n_in,
                              void* d_out, int out_size, void* d_ws, size_t ws_size,
                              hipStream_t stream) {
    const float* feat = (const float*)d_in[0];
    const int* src_c2t = (const int*)d_in[3];
    const int* dst_c2t = (const int*)d_in[4];
    const int* src_m2t = (const int*)d_in[5];
    const int* dst_m2t = (const int*)d_in[6];
    const int* src_t2c = (const int*)d_in[7];
    const int* dst_t2c = (const int*)d_in[8];
    const int* src_t2m = (const int*)d_in[9];
    const int* dst_t2m = (const int*)d_in[10];
    const float* W1_c2t = (const float*)d_in[13];
    const float* b1_c2t = (const float*)d_in[14];
    const float* W1_m2t = (const float*)d_in[17];
    const float* b1_m2t = (const float*)d_in[18];
    const float* W0_t2c = (const float*)d_in[19];
    const float* b0_t2c = (const float*)d_in[20];
    const float* W0_t2m = (const float*)d_in[23];
    const float* b0_t2m = (const float*)d_in[24];
    const float* Wf  = (const float*)d_in[27];
    const float* bfv = (const float*)d_in[28];

    char* ws = (char*)d_ws;
    // Non-overlapping layout, max footprint ~43.5 MB (< 52.6 MB proven safe).
    float* SUM      = (float*)(ws + 0);            // 25.6 MB (50000x128 chunk, reused 3x)
    // four rowPtr arrays adjacent -> ONE memset of 4,480,040 bytes
    int*   rowPtrC  = (int*)(ws + 25600000);       // (NC+1)*4 = 400,016
    int*   rowPtrM  = (int*)(ws + 26000016);       // (NM+1)*4 = 80,016
    int*   rowPtrTC = (int*)(ws + 26080032);       // (NT+1)*4 = 2,000,004
    int*   rowPtrTM = (int*)(ws + 28080036);       // 2,000,004
    int*   cursorC  = (int*)(ws + 30080040);       // 400,000
    int*   cursorM  = (int*)(ws + 30480040);       // 80,000
    int*   cursorTC = (int*)(ws + 30560040);       // 2,000,000
    int*   cursorTM = (int*)(ws + 32560040);       // 2,000,000
    int*   eidxC    = (int*)(ws + 34560040);       // 2,000,000
    int*   eidxM    = (int*)(ws + 36560040);       // 2,000,000
    int*   eidxTC   = (int*)(ws + 38560040);       // 2,000,000
    int*   eidxTM   = (int*)(ws + 40560040);       // 2,000,000
    float* pC       = (float*)(ws + 42560040);     // 800,000 (8B-aligned)
    float* pM       = (float*)(ws + 43360040);     // 160,000
    float* WeqC     = (float*)(ws + 43520040);
    float* WeqM     = (float*)(ws + 43520552);
    float* beq      = (float*)(ws + 43521064);
    int*   blkC     = (int*)(ws + 43521080);       // 98 ints
    int*   blkM     = (int*)(ws + 43521472);       // 20 ints
    int*   blkTC    = (int*)(ws + 43521552);       // 489 ints
    int*   blkTM    = (int*)(ws + 43523508);       // 489 ints -> end ~43.53 MB

    hipMemsetAsync(rowPtrC, 0, 4480040, stream);   // all four rowPtr arrays

    weq_kernel<<<1, 256, 0, stream>>>(W1_c2t, b1_c2t, W1_m2t, b1_m2t, Wf, WeqC, WeqM, beq);

    // ---- build all four CSRs ----
    hist4<<<7813, 256, 0, stream>>>(dst_t2c, dst_t2m, dst_c2t, dst_m2t,
                                    rowPtrC, rowPtrM, rowPtrTC, rowPtrTM);
    blocksum4<<<1096, 256, 0, stream>>>(rowPtrC, rowPtrM, rowPtrTC, rowPtrTM,
                                        blkC, blkM, blkTC, blkTM);
    scanblk4<<<4, 256, 0, stream>>>(blkC, blkM, blkTC, blkTM);
    scanfinal4<<<1096, 256, 0, stream>>>(rowPtrC, cursorC, blkC,
                                         rowPtrM, cursorM, blkM,
                                         rowPtrTC, cursorTC, blkTC,
                                         rowPtrTM, cursorTM, blkTM);
    scatter4<<<7813, 256, 0, stream>>>(src_t2c, dst_t2c, cursorC, eidxC,
                                       src_t2m, dst_t2m, cursorM, eidxM,
                                       src_c2t, dst_c2t, cursorTC, eidxTC,
                                       src_m2t, dst_m2t, cursorTM, eidxTM);

    // ---- layer 0: gather-aggregate + fused projection, chunked ----
    agg_csr<<<12500, 256, 0, stream>>>(feat, rowPtrC, eidxC, SUM, 0, 50000);
    h1proj<<<1563, 256, 0, stream>>>(SUM, rowPtrC, W0_t2c, b0_t2c, WeqC, pC, 50000);
    agg_csr<<<12500, 256, 0, stream>>>(feat, rowPtrC, eidxC, SUM, 50000, 50000);
    h1proj<<<1563, 256, 0, stream>>>(SUM, rowPtrC + 50000, W0_t2c, b0_t2c, WeqC, pC + 100000, 50000);
    agg_csr<<<5000, 256, 0, stream>>>(feat, rowPtrM, eidxM, SUM, 0, 20000);
    h1proj<<<625, 256, 0, stream>>>(SUM, rowPtrM, W0_t2m, b0_t2m, WeqM, pM, 20000);

    // ---- layer 1: atomic-free CSR gather fused with final linear ----
    gather_final<<<1954, 256, 0, stream>>>(pC, rowPtrTC, eidxTC,
                                           pM, rowPtrTM, eidxTM,
                                           beq, bfv, (float*)d_out);
}

// Round 3
// 739.004 us; speedup vs baseline: 1.3360x; 1.1173x over previous
//
#include <hip/hip_runtime.h>
#include <stdint.h>

#define NT 500000
#define NC 100000
#define NM 20000
#define NE 500000

// ---------- small dense precompute: Weq = W1 @ Wf, beq = b1 @ Wf ----------
__global__ __launch_bounds__(256) void weq_kernel(const float* __restrict__ W1c,
                                                  const float* __restrict__ b1c,
                                                  const float* __restrict__ W1m,
                                                  const float* __restrict__ b1m,
                                                  const float* __restrict__ Wf,
                                                  float* __restrict__ WeqC,
                                                  float* __restrict__ WeqM,
                                                  float* __restrict__ beq) {
    int t = threadIdx.x;
    if (t < 128) {
        int k = t >> 1, o = t & 1;
        float s = 0.0f;
        for (int j = 0; j < 64; j++) s += W1c[k * 64 + j] * Wf[j * 2 + o];
        WeqC[k * 2 + o] = s;
    } else {
        int k = (t - 128) >> 1, o = t & 1;
        float s = 0.0f;
        for (int j = 0; j < 64; j++) s += W1m[k * 64 + j] * Wf[j * 2 + o];
        WeqM[k * 2 + o] = s;
    }
    if (t < 4) {
        const float* b = (t < 2) ? b1c : b1m;
        int o = t & 1;
        float s = 0.0f;
        for (int j = 0; j < 64; j++) s += b[j] * Wf[j * 2 + o];
        beq[t] = s;
    }
}

// ---------- linked-chain build: ALL FOUR relations in one launch ----------
// Per edge: old = atomicExch(&head[dst], e); rec[e] = {src, old}.
// rec write is fully coalesced (thread id == edge id). No scan, no scatter.
__global__ __launch_bounds__(256) void chain4(const int* __restrict__ sTC,
                                              const int* __restrict__ dTC,
                                              const int* __restrict__ sTM,
                                              const int* __restrict__ dTM,
                                              const int* __restrict__ sCT,
                                              const int* __restrict__ dCT,
                                              const int* __restrict__ sMT,
                                              const int* __restrict__ dMT,
                                              int* __restrict__ headC,
                                              int* __restrict__ headM,
                                              int* __restrict__ headTC,
                                              int* __restrict__ headTM,
                                              int2* __restrict__ recC,
                                              int2* __restrict__ recM,
                                              int2* __restrict__ recTC,
                                              int2* __restrict__ recTM) {
    int id = blockIdx.x * 256 + threadIdx.x;
    int r = id / NE;
    if (r > 3) return;
    int e = id - r * NE;
    const int* src; const int* dst; int* head; int2* rec;
    if (r == 0)      { src = sTC; dst = dTC; head = headC;  rec = recC; }
    else if (r == 1) { src = sTM; dst = dTM; head = headM;  rec = recM; }
    else if (r == 2) { src = sCT; dst = dCT; head = headTC; rec = recTC; }
    else             { src = sMT; dst = dMT; head = headTM; rec = recTM; }
    int d = dst[e], s = src[e];
    int old = atomicExch(&head[d], e);
    rec[e] = make_int2(s, old);
}

// ---------- chain-walk aggregation: one wave per dst node, no atomics ----------
// 64 lanes x float2 = full 512B feature row per edge; chain-pointer load is
// wave-uniform (coalesces to one request). Degree counted during the walk.
__global__ __launch_bounds__(256) void agg_chain(const float* __restrict__ feat,
                                                 const int* __restrict__ head,
                                                 const int2* __restrict__ rec,
                                                 float* __restrict__ sum,
                                                 int* __restrict__ cntArr,
                                                 int base, int nNodes) {
    int gw = (blockIdx.x * 256 + threadIdx.x) >> 6;
    if (gw >= nNodes) return;
    int lane = threadIdx.x & 63;
    int node = base + gw;
    int e = head[node];
    float ax = 0.0f, ay = 0.0f;
    int cnt = 0;
    const float* fp = feat + lane * 2;
    while (e >= 0) {
        int2 rc = rec[e];
        const float2 v = *(const float2*)(fp + (size_t)rc.x * 128);
        ax += v.x; ay += v.y;
        cnt++;
        e = rc.y;
    }
    float2 o; o.x = ax; o.y = ay;
    *(float2*)(sum + (size_t)gw * 128 + lane * 2) = o;
    if (lane == 0) cntArr[node] = cnt;
}

// ---------- fused: h1 = cnt>0 ? leaky(sum/cnt @ W0 + b0) : 0 ; p = h1 @ Weq ----------
__global__ __launch_bounds__(256) void h1proj(const float* __restrict__ sum,
                                              const int* __restrict__ cntB,
                                              const float* __restrict__ W0,
                                              const float* __restrict__ b0,
                                              const float* __restrict__ Weq,
                                              float* __restrict__ p, int n) {
    __shared__ float Ws[128 * 64];    // 32 KB
    __shared__ float sums[32 * 128];  // 16 KB
    int tid = threadIdx.x;
    int base = blockIdx.x * 32;
    {
        const float4* W4 = (const float4*)W0;
        float4* Ws4 = (float4*)Ws;
        for (int i = tid; i < 128 * 64 / 4; i += 256) Ws4[i] = W4[i];
    }
    {
        const float4* S4 = (const float4*)sum;
        float4* s4 = (float4*)sums;
        for (int i = tid; i < 32 * 128 / 4; i += 256) {
            int r = i >> 5;
            int row = base + r;
            float4 v;
            if (row < n) v = S4[(size_t)base * 32 + i];
            else { v.x = v.y = v.z = v.w = 0.0f; }
            s4[i] = v;
        }
    }
    __syncthreads();
    int col = tid & 63, wv = tid >> 6;
    float acc[8];
#pragma unroll
    for (int r = 0; r < 8; r++) acc[r] = 0.0f;
    const float* srow = &sums[wv * 8 * 128];
    for (int k = 0; k < 128; k += 4) {
        float w0_ = Ws[(k + 0) * 64 + col];
        float w1_ = Ws[(k + 1) * 64 + col];
        float w2_ = Ws[(k + 2) * 64 + col];
        float w3_ = Ws[(k + 3) * 64 + col];
#pragma unroll
        for (int r = 0; r < 8; r++) {
            const float4 s = *(const float4*)&srow[r * 128 + k];
            acc[r] += s.x * w0_ + s.y * w1_ + s.z * w2_ + s.w * w3_;
        }
    }
    float b0c = b0[col];
    float wq0 = Weq[col * 2 + 0], wq1 = Weq[col * 2 + 1];
#pragma unroll
    for (int r = 0; r < 8; r++) {
        int row = base + wv * 8 + r;
        int cn = 0;
        if (row < n) cn = cntB[row];
        float h = 0.0f;
        if (cn > 0) {
            float v = acc[r] / (float)cn + b0c;
            h = v > 0.0f ? v : 0.01f * v;
        }
        float p0 = h * wq0, p1 = h * wq1;
#pragma unroll
        for (int off = 32; off; off >>= 1) {
            p0 += __shfl_down(p0, off, 64);
            p1 += __shfl_down(p1, off, 64);
        }
        if (col == 0 && row < n) {
            p[(size_t)row * 2 + 0] = p0;
            p[(size_t)row * 2 + 1] = p1;
        }
    }
}

// ---------- layer 1: chain gather (no atomics) fused with final linear ----------
// Thread per transaction; avg chain length 1 per relation; pC/pM are L2-resident.
__global__ __launch_bounds__(256) void gather_final(const float* __restrict__ pC,
                                                    const int* __restrict__ headTC,
                                                    const int2* __restrict__ recTC,
                                                    const float* __restrict__ pM,
                                                    const int* __restrict__ headTM,
                                                    const int2* __restrict__ recTM,
                                                    const float* __restrict__ beq,
                                                    const float* __restrict__ bfv,
                                                    float* __restrict__ out) {
    int i = blockIdx.x * 256 + threadIdx.x;
    if (i >= NT) return;
    float r0 = bfv[0], r1 = bfv[1];
    {
        int e = headTC[i];
        if (e >= 0) {
            float a0 = 0.f, a1 = 0.f;
            int c = 0;
            while (e >= 0) {
                int2 rc = recTC[e];
                const float2 v = *(const float2*)(pC + (size_t)rc.x * 2);
                a0 += v.x; a1 += v.y;
                c++;
                e = rc.y;
            }
            float inv = 1.0f / (float)c;
            r0 += a0 * inv + beq[0];
            r1 += a1 * inv + beq[1];
        }
    }
    {
        int e = headTM[i];
        if (e >= 0) {
            float a0 = 0.f, a1 = 0.f;
            int c = 0;
            while (e >= 0) {
                int2 rc = recTM[e];
                const float2 v = *(const float2*)(pM + (size_t)rc.x * 2);
                a0 += v.x; a1 += v.y;
                c++;
                e = rc.y;
            }
            float inv = 1.0f / (float)c;
            r0 += a0 * inv + beq[2];
            r1 += a1 * inv + beq[3];
        }
    }
    float2 o; o.x = r0; o.y = r1;
    *(float2*)(out + (size_t)i * 2) = o;
}

extern "C" void kernel_launch(void* const* d_in, const int* in_sizes, int n_in,
                              void* d_out, int out_size, void* d_ws, size_t ws_size,
                              hipStream_t stream) {
    const float* feat = (const float*)d_in[0];
    const int* src_c2t = (const int*)d_in[3];
    const int* dst_c2t = (const int*)d_in[4];
    const int* src_m2t = (const int*)d_in[5];
    const int* dst_m2t = (const int*)d_in[6];
    const int* src_t2c = (const int*)d_in[7];
    const int* dst_t2c = (const int*)d_in[8];
    const int* src_t2m = (const int*)d_in[9];
    const int* dst_t2m = (const int*)d_in[10];
    const float* W1_c2t = (const float*)d_in[13];
    const float* b1_c2t = (const float*)d_in[14];
    const float* W1_m2t = (const float*)d_in[17];
    const float* b1_m2t = (const float*)d_in[18];
    const float* W0_t2c = (const float*)d_in[19];
    const float* b0_t2c = (const float*)d_in[20];
    const float* W0_t2m = (const float*)d_in[23];
    const float* b0_t2m = (const float*)d_in[24];
    const float* Wf  = (const float*)d_in[27];
    const float* bfv = (const float*)d_in[28];

    char* ws = (char*)d_ws;
    // Footprint ~47.5 MB (< 52.6 MB proven safe).
    float* SUM     = (float*)(ws + 0);            // 25.6 MB (50000x128 chunk, reused 3x)
    // four head arrays adjacent -> ONE 0xFF memset (init to -1)
    int*   headC   = (int*)(ws + 25600000);       // NC*4   = 400,000
    int*   headM   = (int*)(ws + 26000000);       // NM*4   = 80,000
    int*   headTC  = (int*)(ws + 26080000);       // NT*4   = 2,000,000
    int*   headTM  = (int*)(ws + 28080000);       // NT*4   = 2,000,000
    int2*  recC    = (int2*)(ws + 30080000);      // NE*8   = 4,000,000
    int2*  recM    = (int2*)(ws + 34080000);      // 4,000,000
    int2*  recTC   = (int2*)(ws + 38080000);      // 4,000,000
    int2*  recTM   = (int2*)(ws + 42080000);      // 4,000,000
    float* pC      = (float*)(ws + 46080000);     // NC*2*4 = 800,000
    float* pM      = (float*)(ws + 46880000);     // NM*2*4 = 160,000
    int*   cntC    = (int*)(ws + 47040000);       // 400,000
    int*   cntM    = (int*)(ws + 47440000);       // 80,000
    float* WeqC    = (float*)(ws + 47520000);     // 512
    float* WeqM    = (float*)(ws + 47520512);     // 512
    float* beq     = (float*)(ws + 47521024);     // 16 -> end ~47.52 MB

    // init all four head arrays to -1 in one call
    hipMemsetAsync(headC, 0xFF, 4480000, stream);

    weq_kernel<<<1, 256, 0, stream>>>(W1_c2t, b1_c2t, W1_m2t, b1_m2t, Wf, WeqC, WeqM, beq);

    // ---- build all four linked chains in one launch ----
    chain4<<<7813, 256, 0, stream>>>(src_t2c, dst_t2c, src_t2m, dst_t2m,
                                     src_c2t, dst_c2t, src_m2t, dst_m2t,
                                     headC, headM, headTC, headTM,
                                     recC, recM, recTC, recTM);

    // ---- layer 0: chain-walk aggregate + fused projection, chunked ----
    agg_chain<<<12500, 256, 0, stream>>>(feat, headC, recC, SUM, cntC, 0, 50000);
    h1proj<<<1563, 256, 0, stream>>>(SUM, cntC, W0_t2c, b0_t2c, WeqC, pC, 50000);
    agg_chain<<<12500, 256, 0, stream>>>(feat, headC, recC, SUM, cntC, 50000, 50000);
    h1proj<<<1563, 256, 0, stream>>>(SUM, cntC + 50000, W0_t2c, b0_t2c, WeqC, pC + 100000, 50000);
    agg_chain<<<5000, 256, 0, stream>>>(feat, headM, recM, SUM, cntM, 0, 20000);
    h1proj<<<625, 256, 0, stream>>>(SUM, cntM, W0_t2m, b0_t2m, WeqM, pM, 20000);

    // ---- layer 1: chain gather fused with final linear ----
    gather_final<<<1954, 256, 0, stream>>>(pC, headTC, recTC,
                                           pM, headTM, recTM,
                                           beq, bfv, (float*)d_out);
}